// Round 3
// baseline (165.715 us; speedup 1.0000x reference)
//
#include <hip/hip_runtime.h>

#define NROWS 8192
#define BQ    4096
#define DDIM  256
#define INV_T (1.0f/0.07f)
#define K2EXP (1.4426950408889634f/0.07f)   // log2(e)/T

typedef short bf16x8 __attribute__((ext_vector_type(8)));
typedef float f32x4  __attribute__((ext_vector_type(4)));
typedef unsigned short u16;

__device__ __forceinline__ u16 f2bf(float f) {
  unsigned u = __float_as_uint(f);
  u += 0x7fffu + ((u >> 16) & 1u);   // round-to-nearest-even
  return (u16)(u >> 16);
}

// ---------------- kernel 1: L2-normalize rows of [z_i; z_j], cast to bf16 ----
// Also zeroes the scalar output (stream-ordered; loss_kernel runs last).
__global__ void norm_cast_kernel(const float* __restrict__ zi,
                                 const float* __restrict__ zj,
                                 u16* __restrict__ zb,
                                 float* __restrict__ out) {
  if (blockIdx.x == 0 && threadIdx.x == 0) *out = 0.0f;
  int wave = threadIdx.x >> 6;
  int lane = threadIdx.x & 63;
  int row  = blockIdx.x * 4 + wave;            // one wave per row, 4 rows/block
  const float* src = (row < BQ) ? (zi + (size_t)row * DDIM)
                                : (zj + (size_t)(row - BQ) * DDIM);
  float4 v = ((const float4*)src)[lane];       // 64 lanes x float4 = 256
  float s = v.x*v.x + v.y*v.y + v.z*v.z + v.w*v.w;
  #pragma unroll
  for (int m = 32; m; m >>= 1) s += __shfl_xor(s, m, 64);
  float scale = 1.0f / fmaxf(sqrtf(s), 1e-12f);
  ushort4 o;
  o.x = f2bf(v.x * scale); o.y = f2bf(v.y * scale);
  o.z = f2bf(v.z * scale); o.w = f2bf(v.w * scale);
  ((ushort4*)(zb + (size_t)row * DDIM))[lane] = o;
}

// ---------------- kernel 2: fused sim GEMM + mask + pos/negexp row partials --
#define GL2LDS(gp, lp) \
  __builtin_amdgcn_global_load_lds((__attribute__((address_space(1))) void*)(gp), \
                                   (__attribute__((address_space(3))) void*)(lp), 16, 0, 0)

// Round-3 post-mortem: streaming B through a deep REGISTER pipeline (bv[3][4]
// + av[2][4] + 64-f32 acc + 32 partials ~= 210 live) spilled -- compiler kept
// arch VGPRs at 128 and generated 34 MB of scratch writes (59.7 -> 106 us).
// RULE for this kernel: per-kk live set must stay at the round-0 level
// (fresh av[4]/bv[4] read from LDS right before the MFMAs, acc in AGPRs).
// Round 4/5 structure (this file; round-4 bench was an infra failure,
// resubmitted unchanged):
//   * A-tile (128x256 = 64 KB) persistent in LDS, staged ONCE via
//     global_load_lds, chunk-swizzled (slot c holds global chunk c^(row&7));
//     ds_read at (kk,qd) then XORs with row&7 -> 16 lanes spread over 8
//     slots = 2-way = free. (verified correct + conflict-free in round 3)
//   * B staged per-kk into lsB[2] (round-0's proven swizzle, 0 conflicts),
//     double-buffered with PREFETCH DISTANCE 1: iteration t issues
//     global_load_lds for tile t+1, computes t, then ONE __syncthreads.
//     The vmcnt(0) drain in __syncthreads now overlaps 16 MFMAs + 8
//     ds_reads instead of being fully exposed (round-0 was distance 0,
//     2 barriers/kk). Barriers: 128 -> 65.
//   * LDS 64 + 16 KB = 80 KB -> exactly 2 blocks/CU (160 KB), 8 waves/CU.
// NOTE: __launch_bounds__(256) ONLY -- min-waves 4 capped regs at 128/wave
// and spilled the accumulator (round 2: 620 MB scratch). Do not re-add.
__global__ __launch_bounds__(256) void simloss_kernel(
    const u16* __restrict__ zb, const int* __restrict__ labels,
    float* __restrict__ pos_p, float* __restrict__ neg_p) {
  __shared__ __align__(16) u16 lsA[128 * 256];   // persistent A, 64 KB
  __shared__ __align__(16) u16 lsB[2][128 * 32]; // double-buffered B, 16 KB

  const int tid  = threadIdx.x;
  const int w    = tid >> 6;         // wave 0..3
  const int lane = tid & 63;
  const int ln   = lane & 15;        // MFMA n/m lane index
  const int qd   = lane >> 4;        // MFMA quad
  const int wr   = w >> 1;           // wave row (0..1) in 2x2 wave grid
  const int wc   = w & 1;            // wave col
  const int r0   = blockIdx.x * 128; // block row base (64 row tiles)
  const int cb   = blockIdx.y * 1024;// col split base (8 splits)

  // ---- stage A once: rows r0..r0+127, full K=256, chunk-swizzled ----------
  #pragma unroll
  for (int j = 0; j < 16; ++j) {
    int base = w * 32 + j * 2;                 // each instr covers 2 rows
    int row  = base + (lane >> 5);
    int gcol = ((lane & 31) ^ (row & 7)) * 8;  // inverse-swizzled source chunk
    GL2LDS(zb + (size_t)(r0 + row) * DDIM + gcol, &lsA[base * 256]);
  }

  // ---- B staging lane geometry (round-0 proven: 0 bank conflicts) ---------
  const int strow = lane >> 2;       // 16 rows per load instr
  const int slot  = lane & 3;        // LDS chunk position this lane fills
  const int stk   = (slot ^ ((strow >> 1) & 3)) * 8;  // global chunk to fetch
  const int rdsw  = (ln >> 1) & 3;   // read-side swizzle key

  // ---- stage B tile for t=0 (ci=0, kk=0) into lsB[0] ----------------------
  #pragma unroll
  for (int j = 0; j < 2; ++j) {
    int rbase = w * 32 + j * 16;
    GL2LDS(zb + (size_t)(cb + rbase + strow) * DDIM + stk, &lsB[0][rbase * 32]);
  }

  int rowlab[16];
  #pragma unroll
  for (int ri = 0; ri < 4; ++ri)
    #pragma unroll
    for (int r = 0; r < 4; ++r) {
      int row = r0 + wr * 64 + ri * 16 + qd * 4 + r;   // C/D: row = quad*4+reg
      rowlab[ri * 4 + r] = labels[row & (BQ - 1)];     // concat labels = labels[row % B]
    }

  float posA[16], negA[16];
  #pragma unroll
  for (int i = 0; i < 16; ++i) { posA[i] = 0.0f; negA[i] = 0.0f; }

  const int axor = ln & 7;                     // == (local A row) & 7
  int arow[4], brow[4];
  #pragma unroll
  for (int ri = 0; ri < 4; ++ri) arow[ri] = (wr * 64 + ri * 16 + ln) * DDIM;
  #pragma unroll
  for (int mi = 0; mi < 4; ++mi)
    brow[mi] = (wc * 64 + mi * 16 + ln) * 32 + (qd ^ rdsw) * 8;

  __syncthreads();   // drains A-stage + B(t=0) stage

  const f32x4 z4 = {0.f, 0.f, 0.f, 0.f};
  f32x4 acc[4][4];
  int colv[4], clab[4];

  #pragma unroll 2
  for (int t = 0; t < 64; ++t) {               // t = ci*8 + kk; 8 ci x 8 kk
    const int kk = t & 7;
    if (kk == 0) {                             // new column tile: masks + acc=0
      const int c0 = cb + (t >> 3) * 128;
      #pragma unroll
      for (int mi = 0; mi < 4; ++mi) {
        colv[mi] = c0 + wc * 64 + mi * 16 + ln;        // C/D: col = lane&15
        clab[mi] = labels[colv[mi] & (BQ - 1)];
      }
      #pragma unroll
      for (int ri = 0; ri < 4; ++ri)
        #pragma unroll
        for (int mi = 0; mi < 4; ++mi) acc[ri][mi] = z4;
    }

    if (t < 63) {                              // prefetch B tile t+1 (dist 1)
      const int tn  = t + 1;
      const int c0n = cb + (tn >> 3) * 128;
      const int k0n = (tn & 7) * 32;
      u16* dst = &lsB[tn & 1][0];
      #pragma unroll
      for (int j = 0; j < 2; ++j) {
        int rbase = w * 32 + j * 16;
        GL2LDS(zb + (size_t)(c0n + rbase + strow) * DDIM + k0n + stk,
               dst + rbase * 32);
      }
    }

    // fragments fresh from LDS each kk (round-0 register budget, no spill)
    const u16* bb = &lsB[t & 1][0];
    bf16x8 av[4], bv[4];
    #pragma unroll
    for (int ri = 0; ri < 4; ++ri)
      av[ri] = *(const bf16x8*)&lsA[arow[ri] + ((kk * 4 + qd) ^ axor) * 8];
    #pragma unroll
    for (int mi = 0; mi < 4; ++mi)
      bv[mi] = *(const bf16x8*)&bb[brow[mi]];
    #pragma unroll
    for (int ri = 0; ri < 4; ++ri)
      #pragma unroll
      for (int mi = 0; mi < 4; ++mi)
        acc[ri][mi] = __builtin_amdgcn_mfma_f32_16x16x32_bf16(
            av[ri], bv[mi], acc[ri][mi], 0, 0, 0);

    if (kk == 7) {                             // fused epilogue for this ci
      const int c0 = cb + (t >> 3) * 128;
      if (r0 == c0) {                          // diagonal blocks: self-exclude
        #pragma unroll
        for (int ri = 0; ri < 4; ++ri)
          #pragma unroll
          for (int mi = 0; mi < 4; ++mi) {
            f32x4 v = acc[ri][mi];
            #pragma unroll
            for (int r = 0; r < 4; ++r) {
              int slt = ri * 4 + r;
              float s = v[r];
              bool same = (rowlab[slt] == clab[mi]);
              bool diag = ((r0 + wr * 64 + ri * 16 + qd * 4 + r) == colv[mi]);
              posA[slt] += (same && !diag) ? s : 0.0f;
              negA[slt] += same ? 0.0f : __builtin_amdgcn_exp2f(s * K2EXP);
            }
          }
      } else {
        #pragma unroll
        for (int ri = 0; ri < 4; ++ri)
          #pragma unroll
          for (int mi = 0; mi < 4; ++mi) {
            f32x4 v = acc[ri][mi];
            #pragma unroll
            for (int r = 0; r < 4; ++r) {
              int slt = ri * 4 + r;
              float s = v[r];
              bool same = (rowlab[slt] == clab[mi]);
              posA[slt] += same ? s : 0.0f;
              negA[slt] += same ? 0.0f : __builtin_amdgcn_exp2f(s * K2EXP);
            }
          }
      }
    }

    __syncthreads();   // one barrier per t: drains prefetch + guards lsB reuse
  }

  // reduce over the 16 lanes (ln) that hold different cols of the same row
  #pragma unroll
  for (int i = 0; i < 16; ++i) {
    #pragma unroll
    for (int m = 1; m < 16; m <<= 1) {
      posA[i] += __shfl_xor(posA[i], m, 64);
      negA[i] += __shfl_xor(negA[i], m, 64);
    }
  }
  if (ln == 0) {
    int s = blockIdx.y * 2 + wc;               // 16 disjoint slices
    #pragma unroll
    for (int i = 0; i < 16; ++i) {
      int row = r0 + wr * 64 + (i >> 2) * 16 + qd * 4 + (i & 3);
      pos_p[(size_t)s * NROWS + row] = posA[i];
      neg_p[(size_t)s * NROWS + row] = negA[i];
    }
  }
}

// ---------------- kernel 3: per-row loss + mean (parallel, atomic) -----------
__global__ void loss_kernel(const float* __restrict__ pos_p,
                            const float* __restrict__ neg_p,
                            float* __restrict__ out) {
  int row = blockIdx.x * 256 + threadIdx.x;      // 32 blocks x 256 threads
  float p = 0.0f, n = 0.0f;
  #pragma unroll
  for (int s = 0; s < 16; ++s) {
    p += pos_p[(size_t)s * NROWS + row];
    n += neg_p[(size_t)s * NROWS + row];
  }
  float l = log1pf(expf(logf(n) - p * INV_T));
  #pragma unroll
  for (int m = 32; m; m >>= 1) l += __shfl_xor(l, m, 64);
  __shared__ float red[4];
  if ((threadIdx.x & 63) == 0) red[threadIdx.x >> 6] = l;
  __syncthreads();
  if (threadIdx.x == 0) {
    float tot = red[0] + red[1] + red[2] + red[3];
    atomicAdd(out, tot * (1.0f / NROWS));
  }
}

// ---------------- launcher ---------------------------------------------------
extern "C" void kernel_launch(void* const* d_in, const int* in_sizes, int n_in,
                              void* d_out, int out_size, void* d_ws, size_t ws_size,
                              hipStream_t stream) {
  const float* zi     = (const float*)d_in[0];
  const float* zj     = (const float*)d_in[1];
  const int*   labels = (const int*)d_in[2];
  float*       out    = (float*)d_out;

  char* w = (char*)d_ws;
  u16*   zb    = (u16*)w;                                          // 4 MB bf16 Z
  float* pos_p = (float*)(w + (size_t)NROWS * DDIM * sizeof(u16)); // 16x8192 f32
  float* neg_p = pos_p + 16 * NROWS;                               // 16x8192 f32

  hipLaunchKernelGGL(norm_cast_kernel, dim3(2048), dim3(256), 0, stream,
                     zi, zj, zb, out);
  hipLaunchKernelGGL(simloss_kernel, dim3(64, 8), dim3(256), 0, stream,
                     zb, labels, pos_p, neg_p);
  hipLaunchKernelGGL(loss_kernel, dim3(32), dim3(256), 0, stream,
                     pos_p, neg_p, out);
}

// Round 4
// 157.939 us; speedup vs baseline: 1.0492x; 1.0492x over previous
//
#include <hip/hip_runtime.h>

#define NROWS 8192
#define BQ    4096
#define DDIM  256
#define INV_T (1.0f/0.07f)
#define K2EXP (1.4426950408889634f/0.07f)   // log2(e)/T

typedef short bf16x8 __attribute__((ext_vector_type(8)));
typedef float f32x4  __attribute__((ext_vector_type(4)));
typedef unsigned short u16;

__device__ __forceinline__ u16 f2bf(float f) {
  unsigned u = __float_as_uint(f);
  u += 0x7fffu + ((u >> 16) & 1u);   // round-to-nearest-even
  return (u16)(u >> 16);
}

// ---------------- kernel 1: L2-normalize rows of [z_i; z_j], cast to bf16 ----
// Also zeroes the scalar output (stream-ordered; loss_kernel runs last).
__global__ void norm_cast_kernel(const float* __restrict__ zi,
                                 const float* __restrict__ zj,
                                 u16* __restrict__ zb,
                                 float* __restrict__ out) {
  if (blockIdx.x == 0 && threadIdx.x == 0) *out = 0.0f;
  int wave = threadIdx.x >> 6;
  int lane = threadIdx.x & 63;
  int row  = blockIdx.x * 4 + wave;            // one wave per row, 4 rows/block
  const float* src = (row < BQ) ? (zi + (size_t)row * DDIM)
                                : (zj + (size_t)(row - BQ) * DDIM);
  float4 v = ((const float4*)src)[lane];       // 64 lanes x float4 = 256
  float s = v.x*v.x + v.y*v.y + v.z*v.z + v.w*v.w;
  #pragma unroll
  for (int m = 32; m; m >>= 1) s += __shfl_xor(s, m, 64);
  float scale = 1.0f / fmaxf(sqrtf(s), 1e-12f);
  ushort4 o;
  o.x = f2bf(v.x * scale); o.y = f2bf(v.y * scale);
  o.z = f2bf(v.z * scale); o.w = f2bf(v.w * scale);
  ((ushort4*)(zb + (size_t)row * DDIM))[lane] = o;
}

// ---------------- kernel 2: fused sim GEMM + mask + pos/negexp row partials --
#define GL2LDS(gp, lp) \
  __builtin_amdgcn_global_load_lds((__attribute__((address_space(1))) void*)(gp), \
                                   (__attribute__((address_space(3))) void*)(lp), 16, 0, 0)

// Round-4 post-mortem ledger:
//  * r2 (min-waves 4): 128-reg cap spilled acc -> 620 MB scratch. Never again.
//  * r3 (B in deep reg pipeline): ~210 live regs -> 34 MB scratch, 106 us.
//  * r5 (persistent 64KB A + dynamic t-loop): occupancy 19%->11% (2 blk/CU),
//    dynamic kk doubled VALU cycles -> 103 us. Persistent-A is a net loser.
// This version = round-0 geometry (16KB-class LDS tiles, VGPR~128, inner kk
// FULLY unrolled so all offsets are immediates, fresh av/bv per kk) plus:
//  * double-buffered lsA/lsB, prefetch distance 1, ONE barrier per K-step:
//      [vmcnt(0): drains prefetch issued a FULL STEP ago -- latency hidden
//       under 16 MFMA + 8 ds_read + epilogue] [s_barrier] [sched_barrier]
//      [issue prefetch(kk+1) -> buf^1] [ds_read buf] [MFMA]
//    Race-safe: passing barrier(k) implies a wave's MFMAs issued, hence its
//    ds_reads of buf^1 retired -> post-barrier DMA into buf^1 cannot race.
//    Pre-barrier per-wave vmcnt(0) makes all waves' slices of buf visible.
//  * labels cached in LDS (4 KB, staged once): the K-loop contains ZERO
//    compiler-tracked vmem loads, so the compiler cannot insert its own
//    vmcnt wait (which would drain the prefetch). rowlab regs are pinned
//    with asm "+v" before the loop for the same reason.
//  * LDS 36 KB, swizzle identical to round-0 (measured 0 bank conflicts).
__global__ __launch_bounds__(256) void simloss_kernel(
    const u16* __restrict__ zb, const int* __restrict__ labels,
    float* __restrict__ pos_p, float* __restrict__ neg_p) {
  __shared__ __align__(16) u16 lsA[2][128 * 32];   // 8 KB x2
  __shared__ __align__(16) u16 lsB[2][128 * 32];   // 8 KB x2
  __shared__ __align__(16) int lsLab[1024];        // this block's col labels

  const int tid  = threadIdx.x;
  const int w    = tid >> 6;         // wave 0..3
  const int lane = tid & 63;
  const int ln   = lane & 15;        // MFMA n/m lane index
  const int qd   = lane >> 4;        // MFMA quad
  const int wr   = w >> 1;           // wave row (0..1) in 2x2 wave grid
  const int wc   = w & 1;            // wave col
  const int r0   = blockIdx.x * 128; // block row base (64 row tiles)
  const int cb   = blockIdx.y * 1024;// col split base (8 splits)
  const int cbm  = cb & (BQ - 1);    // label base for cols (contiguous 1024)

  // staging lane geometry (round-0 proven: 0 bank conflicts)
  const int strow = lane >> 2;       // 16 rows per load instr
  const int slot  = lane & 3;        // LDS chunk position this lane fills
  const int stk   = (slot ^ ((strow >> 1) & 3)) * 8;  // global chunk to fetch
  const int rdsw  = (ln >> 1) & 3;   // read-side swizzle key

  // per-wave global staging base pointers (two 16-row halves per wave)
  const u16* gA0 = zb + (size_t)(r0 + w * 32 +  0 + strow) * DDIM + stk;
  const u16* gA1 = zb + (size_t)(r0 + w * 32 + 16 + strow) * DDIM + stk;
  const u16* gB0 = zb + (size_t)(cb + w * 32 +  0 + strow) * DDIM + stk;
  const u16* gB1 = zb + (size_t)(cb + w * 32 + 16 + strow) * DDIM + stk;

  // ---- prologue: col labels -> LDS, tile(ci=0,kk=0) -> buf 0 --------------
  GL2LDS(labels + cbm + w * 256 + lane * 4, &lsLab[w * 256]);
  GL2LDS(gA0, &lsA[0][(w * 32 +  0) * 32]);
  GL2LDS(gA1, &lsA[0][(w * 32 + 16) * 32]);
  GL2LDS(gB0, &lsB[0][(w * 32 +  0) * 32]);
  GL2LDS(gB1, &lsB[0][(w * 32 + 16) * 32]);

  int rowlab[16];
  #pragma unroll
  for (int ri = 0; ri < 4; ++ri)
    #pragma unroll
    for (int r = 0; r < 4; ++r) {
      int row = r0 + wr * 64 + ri * 16 + qd * 4 + r;   // C/D: row = quad*4+reg
      rowlab[ri * 4 + r] = labels[row & (BQ - 1)];     // concat labels = labels[row % B]
    }
  #pragma unroll
  for (int i = 0; i < 16; ++i) asm volatile("" : "+v"(rowlab[i]));  // settle now

  float posA[16], negA[16];
  #pragma unroll
  for (int i = 0; i < 16; ++i) { posA[i] = 0.0f; negA[i] = 0.0f; }

  int arow[4], brow[4];
  #pragma unroll
  for (int ri = 0; ri < 4; ++ri)
    arow[ri] = (wr * 64 + ri * 16 + ln) * 32 + (qd ^ rdsw) * 8;
  #pragma unroll
  for (int mi = 0; mi < 4; ++mi)
    brow[mi] = (wc * 64 + mi * 16 + ln) * 32 + (qd ^ rdsw) * 8;

  const f32x4 z4 = {0.f, 0.f, 0.f, 0.f};

  for (int ci = 0; ci < 8; ++ci) {             // 8 x 128 cols per block
    int colv[4], clab[4];
    f32x4 acc[4][4];
    #pragma unroll
    for (int mi = 0; mi < 4; ++mi) {
      int cl = ci * 128 + wc * 64 + mi * 16 + ln;
      colv[mi] = cb + cl;                      // C/D: col = lane&15
      clab[mi] = lsLab[cl];                    // LDS, not vmem
    }
    #pragma unroll
    for (int ri = 0; ri < 4; ++ri)
      #pragma unroll
      for (int mi = 0; mi < 4; ++mi) acc[ri][mi] = z4;

    #pragma unroll
    for (int kk = 0; kk < 8; ++kk) {           // K = 256, BK = 32, unrolled
      // wait own prefetched tile complete (issued one full step ago), then
      // block barrier so every wave's slice is visible
      asm volatile("s_waitcnt vmcnt(0)" ::: "memory");
      __builtin_amdgcn_s_barrier();
      __builtin_amdgcn_sched_barrier(0);

      // issue prefetch of next tile into the other buffer (safe post-barrier)
      if (kk < 7) {
        GL2LDS(gA0 + (kk + 1) * 32, &lsA[(kk + 1) & 1][(w * 32 +  0) * 32]);
        GL2LDS(gA1 + (kk + 1) * 32, &lsA[(kk + 1) & 1][(w * 32 + 16) * 32]);
        GL2LDS(gB0 + (kk + 1) * 32, &lsB[(kk + 1) & 1][(w * 32 +  0) * 32]);
        GL2LDS(gB1 + (kk + 1) * 32, &lsB[(kk + 1) & 1][(w * 32 + 16) * 32]);
      } else if (ci < 7) {                     // next ci, kk=0 (A repeats)
        gB0 += 128 * DDIM; gB1 += 128 * DDIM;
        GL2LDS(gA0, &lsA[0][(w * 32 +  0) * 32]);
        GL2LDS(gA1, &lsA[0][(w * 32 + 16) * 32]);
        GL2LDS(gB0, &lsB[0][(w * 32 +  0) * 32]);
        GL2LDS(gB1, &lsB[0][(w * 32 + 16) * 32]);
      }

      // fragments fresh from LDS each kk (round-0 register budget, no spill)
      const u16* la = lsA[kk & 1];
      const u16* lb = lsB[kk & 1];
      bf16x8 av[4], bv[4];
      #pragma unroll
      for (int ri = 0; ri < 4; ++ri) av[ri] = *(const bf16x8*)&la[arow[ri]];
      #pragma unroll
      for (int mi = 0; mi < 4; ++mi) bv[mi] = *(const bf16x8*)&lb[brow[mi]];
      #pragma unroll
      for (int ri = 0; ri < 4; ++ri)
        #pragma unroll
        for (int mi = 0; mi < 4; ++mi)
          acc[ri][mi] = __builtin_amdgcn_mfma_f32_16x16x32_bf16(
              av[ri], bv[mi], acc[ri][mi], 0, 0, 0);
    }

    // fused epilogue: mask + accumulate per-row pos (raw dot) and neg (exp).
    // Runs between kk=7's MFMAs and the next ci's first barrier -> extra
    // cover for the in-flight (ci+1,0) prefetch.
    const int c0 = cb + ci * 128;
    if (r0 == c0) {                            // diagonal blocks: self-exclude
      #pragma unroll
      for (int ri = 0; ri < 4; ++ri)
        #pragma unroll
        for (int mi = 0; mi < 4; ++mi) {
          f32x4 v = acc[ri][mi];
          #pragma unroll
          for (int r = 0; r < 4; ++r) {
            int slt = ri * 4 + r;
            float s = v[r];
            bool same = (rowlab[slt] == clab[mi]);
            bool diag = ((r0 + wr * 64 + ri * 16 + qd * 4 + r) == colv[mi]);
            posA[slt] += (same && !diag) ? s : 0.0f;
            negA[slt] += same ? 0.0f : __builtin_amdgcn_exp2f(s * K2EXP);
          }
        }
    } else {
      #pragma unroll
      for (int ri = 0; ri < 4; ++ri)
        #pragma unroll
        for (int mi = 0; mi < 4; ++mi) {
          f32x4 v = acc[ri][mi];
          #pragma unroll
          for (int r = 0; r < 4; ++r) {
            int slt = ri * 4 + r;
            float s = v[r];
            bool same = (rowlab[slt] == clab[mi]);
            posA[slt] += same ? s : 0.0f;
            negA[slt] += same ? 0.0f : __builtin_amdgcn_exp2f(s * K2EXP);
          }
        }
    }
  }

  // reduce over the 16 lanes (ln) that hold different cols of the same row
  #pragma unroll
  for (int i = 0; i < 16; ++i) {
    #pragma unroll
    for (int m = 1; m < 16; m <<= 1) {
      posA[i] += __shfl_xor(posA[i], m, 64);
      negA[i] += __shfl_xor(negA[i], m, 64);
    }
  }
  if (ln == 0) {
    int s = blockIdx.y * 2 + wc;               // 16 disjoint slices
    #pragma unroll
    for (int i = 0; i < 16; ++i) {
      int row = r0 + wr * 64 + (i >> 2) * 16 + qd * 4 + (i & 3);
      pos_p[(size_t)s * NROWS + row] = posA[i];
      neg_p[(size_t)s * NROWS + row] = negA[i];
    }
  }
}

// ---------------- kernel 3: per-row loss + mean (parallel, atomic) -----------
__global__ void loss_kernel(const float* __restrict__ pos_p,
                            const float* __restrict__ neg_p,
                            float* __restrict__ out) {
  int row = blockIdx.x * 256 + threadIdx.x;      // 32 blocks x 256 threads
  float p = 0.0f, n = 0.0f;
  #pragma unroll
  for (int s = 0; s < 16; ++s) {
    p += pos_p[(size_t)s * NROWS + row];
    n += neg_p[(size_t)s * NROWS + row];
  }
  float l = log1pf(expf(logf(n) - p * INV_T));
  #pragma unroll
  for (int m = 32; m; m >>= 1) l += __shfl_xor(l, m, 64);
  __shared__ float red[4];
  if ((threadIdx.x & 63) == 0) red[threadIdx.x >> 6] = l;
  __syncthreads();
  if (threadIdx.x == 0) {
    float tot = red[0] + red[1] + red[2] + red[3];
    atomicAdd(out, tot * (1.0f / NROWS));
  }
}

// ---------------- launcher ---------------------------------------------------
extern "C" void kernel_launch(void* const* d_in, const int* in_sizes, int n_in,
                              void* d_out, int out_size, void* d_ws, size_t ws_size,
                              hipStream_t stream) {
  const float* zi     = (const float*)d_in[0];
  const float* zj     = (const float*)d_in[1];
  const int*   labels = (const int*)d_in[2];
  float*       out    = (float*)d_out;

  char* w = (char*)d_ws;
  u16*   zb    = (u16*)w;                                          // 4 MB bf16 Z
  float* pos_p = (float*)(w + (size_t)NROWS * DDIM * sizeof(u16)); // 16x8192 f32
  float* neg_p = pos_p + 16 * NROWS;                               // 16x8192 f32

  hipLaunchKernelGGL(norm_cast_kernel, dim3(2048), dim3(256), 0, stream,
                     zi, zj, zb, out);
  hipLaunchKernelGGL(simloss_kernel, dim3(64, 8), dim3(256), 0, stream,
                     zb, labels, pos_p, neg_p);
  hipLaunchKernelGGL(loss_kernel, dim3(32), dim3(256), 0, stream,
                     pos_p, neg_p, out);
}

// Round 5
// 134.922 us; speedup vs baseline: 1.2282x; 1.1706x over previous
//
#include <hip/hip_runtime.h>

#define NROWS 8192
#define BQ    4096
#define DDIM  256
#define NSLC  32
#define INV_T (1.0f/0.07f)
#define K2EXP (1.4426950408889634f/0.07f)   // log2(e)/T

typedef short bf16x8 __attribute__((ext_vector_type(8)));
typedef float f32x4  __attribute__((ext_vector_type(4)));
typedef unsigned short u16;

__device__ __forceinline__ u16 f2bf(float f) {
  unsigned u = __float_as_uint(f);
  u += 0x7fffu + ((u >> 16) & 1u);   // round-to-nearest-even
  return (u16)(u >> 16);
}

// ---------------- kernel 1: L2-normalize rows of [z_i; z_j], cast to bf16 ----
// Also zeroes the scalar output (stream-ordered; loss_kernel runs last).
__global__ void norm_cast_kernel(const float* __restrict__ zi,
                                 const float* __restrict__ zj,
                                 u16* __restrict__ zb,
                                 float* __restrict__ out) {
  if (blockIdx.x == 0 && threadIdx.x == 0) *out = 0.0f;
  int wave = threadIdx.x >> 6;
  int lane = threadIdx.x & 63;
  int row  = blockIdx.x * 4 + wave;            // one wave per row, 4 rows/block
  const float* src = (row < BQ) ? (zi + (size_t)row * DDIM)
                                : (zj + (size_t)(row - BQ) * DDIM);
  float4 v = ((const float4*)src)[lane];       // 64 lanes x float4 = 256
  float s = v.x*v.x + v.y*v.y + v.z*v.z + v.w*v.w;
  #pragma unroll
  for (int m = 32; m; m >>= 1) s += __shfl_xor(s, m, 64);
  float scale = 1.0f / fmaxf(sqrtf(s), 1e-12f);
  ushort4 o;
  o.x = f2bf(v.x * scale); o.y = f2bf(v.y * scale);
  o.z = f2bf(v.z * scale); o.w = f2bf(v.w * scale);
  ((ushort4*)(zb + (size_t)row * DDIM))[lane] = o;
}

// ---------------- kernel 2: fused sim GEMM + mask + pos/negexp row partials --
#define GL2LDS(gp, lp) \
  __builtin_amdgcn_global_load_lds((__attribute__((address_space(1))) void*)(gp), \
                                   (__attribute__((address_space(3))) void*)(lp), 16, 0, 0)

// LEDGER (do not re-try):
//  * r2 min-waves-4 launch bound: 128-reg cap spilled acc -> 620 MB scratch.
//  * r1/r3 deep REGISTER pipeline for B: ~210 live regs -> 34 MB scratch, 106us.
//  * r3/r5 persistent 64KB A-tile: 2 blk/CU, occupancy 11%, 103us.
//  * r4 manual vmcnt(0)/s_barrier/sched_barrier dbuf pipeline: VGPR 128->180,
//    occupancy 10.8%, MfmaUtil 13.6%, 96us. Strict serial chain + fewer waves.
//  CONCLUSION: every intra-block scheduling trick lost to the simple form;
//  losses correlate 1:1 with occupancy. This file = round-0 body VERBATIM
//  (2 barriers/step, distance-0 staging, VGPR 128, measured 0 bank conflicts,
//  59.7us at occupancy 19.4%) with ONE change: column splits 8 -> 16
//  (cb = blockIdx.y*512, 4 ci) so the grid is 1024 blocks = 4 blocks/CU
//  (the VGPR-128/LDS-16KB resource cap), doubling resident waves. Staging
//  and fragment LDS traffic are invariant under the split (they scale with
//  output tiles); only the ~1KB per-block epilogue duplicates.
__global__ __launch_bounds__(256) void simloss_kernel(
    const u16* __restrict__ zb, const int* __restrict__ labels,
    float* __restrict__ pos_p, float* __restrict__ neg_p) {
  // row-major [128][32] bf16, chunk-SWIZZLED: row r's 8-elt chunk c lives at
  // slot c ^ ((r>>1)&3). Banks repeat every 2 rows (128B), so keying on r>>1
  // spreads each quad's 16 lanes over all 16 bank-groups -> 2-way = free.
  // (measured: SQ_LDS_BANK_CONFLICT = 0)
  __shared__ __align__(16) u16 lsA[128 * 32];
  __shared__ __align__(16) u16 lsB[128 * 32];

  const int tid  = threadIdx.x;
  const int w    = tid >> 6;         // wave 0..3
  const int lane = tid & 63;
  const int ln   = lane & 15;        // MFMA n/m lane index
  const int qd   = lane >> 4;        // MFMA quad
  const int wr   = w >> 1;           // wave row (0..1) in 2x2 wave grid
  const int wc   = w & 1;            // wave col
  const int r0   = blockIdx.x * 128; // block row base (64 row tiles)
  const int cb   = blockIdx.y * 512; // col split base (16 splits)

  const int strow = lane >> 2;       // staging: 16 rows per load instr
  const int slot  = lane & 3;        // LDS chunk position this lane fills
  const int stk   = (slot ^ ((strow >> 1) & 3)) * 8;  // global chunk to fetch
  const int rdsw  = (ln >> 1) & 3;   // read-side swizzle key

  int rowidx[16], rowlab[16];
  #pragma unroll
  for (int ri = 0; ri < 4; ++ri)
    #pragma unroll
    for (int r = 0; r < 4; ++r) {
      int slt = ri * 4 + r;
      int row = r0 + wr * 64 + ri * 16 + qd * 4 + r;   // C/D: row = quad*4+reg
      rowidx[slt] = row;
      rowlab[slt] = labels[row & (BQ - 1)];            // concat labels = labels[row % B]
    }

  float posA[16], negA[16];
  #pragma unroll
  for (int i = 0; i < 16; ++i) { posA[i] = 0.0f; negA[i] = 0.0f; }

  for (int ci = 0; ci < 4; ++ci) {               // 4 x 128 cols per block
    const int c0 = cb + ci * 128;
    int colv[4], clab[4];
    #pragma unroll
    for (int mi = 0; mi < 4; ++mi) {
      colv[mi] = c0 + wc * 64 + mi * 16 + ln;    // C/D: col = lane&15
      clab[mi] = labels[colv[mi] & (BQ - 1)];
    }

    const f32x4 z4 = {0.f, 0.f, 0.f, 0.f};
    f32x4 acc[4][4];
    #pragma unroll
    for (int ri = 0; ri < 4; ++ri)
      #pragma unroll
      for (int mi = 0; mi < 4; ++mi) acc[ri][mi] = z4;

    for (int kk = 0; kk < 8; ++kk) {             // K = 256, BK = 32
      const int k0 = kk * 32;
      #pragma unroll
      for (int j = 0; j < 2; ++j) {              // wave stages 32 rows of A and B
        int rbase = w * 32 + j * 16;
        const u16* ga = zb + (size_t)(r0 + rbase + strow) * DDIM + k0 + stk;
        GL2LDS(ga, &lsA[rbase * 32]);
        const u16* gb = zb + (size_t)(c0 + rbase + strow) * DDIM + k0 + stk;
        GL2LDS(gb, &lsB[rbase * 32]);
      }
      __syncthreads();                           // drains vmcnt before barrier

      bf16x8 av[4], bv[4];
      #pragma unroll
      for (int ri = 0; ri < 4; ++ri)             // A[m=ln][k=qd*8+j], swizzled slot
        av[ri] = *(const bf16x8*)&lsA[(wr * 64 + ri * 16 + ln) * 32 + (qd ^ rdsw) * 8];
      #pragma unroll
      for (int mi = 0; mi < 4; ++mi)             // B[n=ln][k=qd*8+j] (B^T input)
        bv[mi] = *(const bf16x8*)&lsB[(wc * 64 + mi * 16 + ln) * 32 + (qd ^ rdsw) * 8];
      #pragma unroll
      for (int ri = 0; ri < 4; ++ri)
        #pragma unroll
        for (int mi = 0; mi < 4; ++mi)
          acc[ri][mi] = __builtin_amdgcn_mfma_f32_16x16x32_bf16(
              av[ri], bv[mi], acc[ri][mi], 0, 0, 0);
      __syncthreads();
    }

    // fused epilogue: mask + accumulate per-row pos (raw dot) and neg (exp)
    #pragma unroll
    for (int ri = 0; ri < 4; ++ri)
      #pragma unroll
      for (int mi = 0; mi < 4; ++mi) {
        f32x4 v = acc[ri][mi];
        #pragma unroll
        for (int r = 0; r < 4; ++r) {
          int slt = ri * 4 + r;
          float s = v[r];
          bool same = (rowlab[slt] == clab[mi]);
          bool diag = (rowidx[slt] == colv[mi]);
          posA[slt] += (same && !diag) ? s : 0.0f;
          negA[slt] += same ? 0.0f : __builtin_amdgcn_exp2f(s * K2EXP);
        }
      }
  }

  // reduce over the 16 lanes (ln) that hold different cols of the same row
  #pragma unroll
  for (int i = 0; i < 16; ++i) {
    #pragma unroll
    for (int m = 1; m < 16; m <<= 1) {
      posA[i] += __shfl_xor(posA[i], m, 64);
      negA[i] += __shfl_xor(negA[i], m, 64);
    }
  }
  if (ln == 0) {
    int s = blockIdx.y * 2 + wc;                 // 32 disjoint slices
    #pragma unroll
    for (int i = 0; i < 16; ++i) {
      pos_p[(size_t)s * NROWS + rowidx[i]] = posA[i];
      neg_p[(size_t)s * NROWS + rowidx[i]] = negA[i];
    }
  }
}

// ---------------- kernel 3: per-row loss + mean (parallel, atomic) -----------
__global__ void loss_kernel(const float* __restrict__ pos_p,
                            const float* __restrict__ neg_p,
                            float* __restrict__ out) {
  int row = blockIdx.x * 256 + threadIdx.x;      // 32 blocks x 256 threads
  float p = 0.0f, n = 0.0f;
  #pragma unroll
  for (int s = 0; s < NSLC; ++s) {
    p += pos_p[(size_t)s * NROWS + row];
    n += neg_p[(size_t)s * NROWS + row];
  }
  float l = log1pf(expf(logf(n) - p * INV_T));
  #pragma unroll
  for (int m = 32; m; m >>= 1) l += __shfl_xor(l, m, 64);
  __shared__ float red[4];
  if ((threadIdx.x & 63) == 0) red[threadIdx.x >> 6] = l;
  __syncthreads();
  if (threadIdx.x == 0) {
    float tot = red[0] + red[1] + red[2] + red[3];
    atomicAdd(out, tot * (1.0f / NROWS));
  }
}

// ---------------- launcher ---------------------------------------------------
extern "C" void kernel_launch(void* const* d_in, const int* in_sizes, int n_in,
                              void* d_out, int out_size, void* d_ws, size_t ws_size,
                              hipStream_t stream) {
  const float* zi     = (const float*)d_in[0];
  const float* zj     = (const float*)d_in[1];
  const int*   labels = (const int*)d_in[2];
  float*       out    = (float*)d_out;

  char* w = (char*)d_ws;
  u16*   zb    = (u16*)w;                                          // 4 MB bf16 Z
  float* pos_p = (float*)(w + (size_t)NROWS * DDIM * sizeof(u16)); // 32x8192 f32
  float* neg_p = pos_p + NSLC * NROWS;                             // 32x8192 f32

  hipLaunchKernelGGL(norm_cast_kernel, dim3(2048), dim3(256), 0, stream,
                     zi, zj, zb, out);
  hipLaunchKernelGGL(simloss_kernel, dim3(64, 16), dim3(256), 0, stream,
                     zb, labels, pos_p, neg_p);
  hipLaunchKernelGGL(loss_kernel, dim3(32), dim3(256), 0, stream,
                     pos_p, neg_p, out);
}